// Round 6
// baseline (745.208 us; speedup 1.0000x reference)
//
#include <hip/hip_runtime.h>

// Trilinear sampling of tsdf/weights volumes at M = B*H*N points.
// D = 256 fixed (reference). Outputs concatenated flat in d_out as float32:
//   [0,        M)   fusion_values
//   [M,      25M)   indices  (M,8,3) -- stored as float-valued integers
//   [25M,    33M)   weights  (M,8)
//   [33M,    34M)   fusion_weights
//
// v5 (resubmit; round-5 bench died to a container-acquire failure, not the
//   kernel): z-duplicated pair layout. Each voxel entry is 16 B:
//       (t(z), w(z), t(z+1), w(z+1))
//   so each of the 4 corner z-pairs is ONE aligned 16 B gather instead of
//   two 8 B gathers: requests/point 8 -> 4. 2x2 xy-bricking keeps one 64 B
//   sector = {2x2 xy} x {z-pair}: expected sectors/pt 2.25 (v4: 2.67).
//   Entry index: ((( (x>>1)*128 + (y>>1) ) * 256 + zlo ) * 4 + (x&1)*2+(y&1)).
//   Rationale: v3->v4 cut gather HBM bytes 33% for only -3.5% time -- the
//   wall is per-line request handling, not bytes. This halves requests.
//   Workspace: exactly 256 MiB; falls back to v4 (134 MB) then v1.

typedef float v2f __attribute__((ext_vector_type(2)));
typedef float v4f __attribute__((ext_vector_type(4)));

// ---------------- v5 pack: one thread per (xy-brick, z) 64 B sector --------
__global__ __launch_bounds__(256) void pack_zdup_kernel(
    const float* __restrict__ tsdf,
    const float* __restrict__ wvol,
    float* __restrict__ packed)          // 16384 bricks * 256 z * 4 * v4f
{
    const int t = blockIdx.x * 256 + threadIdx.x;   // 16384*256 threads
    const int z  = t & 255;                          // fast index -> coalesced
    const int brick = t >> 8;                        // bx*128 + by
    const int y0 = (brick & 127) << 1;
    const int x0 = (brick >> 7) << 1;
    const int z1 = min(z + 1, 255);

    float* __restrict__ dst = packed + ((size_t)t << 4);  // 64 B / thread
#pragma unroll
    for (int dx = 0; dx < 2; ++dx) {
#pragma unroll
        for (int dy = 0; dy < 2; ++dy) {
            const size_t base = ((size_t)(x0 + dx) << 16) |
                                ((size_t)(y0 + dy) << 8);
            v4f e;
            e.x = tsdf[base + z];
            e.y = wvol[base + z];
            e.z = tsdf[base + z1];
            e.w = wvol[base + z1];
            *reinterpret_cast<v4f*>(dst + ((dx * 2 + dy) << 2)) = e;
        }
    }
}

// ---------------- v5 extractor: 4 x 16 B gathers per point -----------------
__global__ __launch_bounds__(256) void extractor_zdup(
    const float* __restrict__ points,
    const float* __restrict__ packed,
    float* __restrict__ out,
    int M)
{
    const int m = blockIdx.x * 256 + threadIdx.x;
    if (m >= M) return;

    const size_t p3 = 3ull * (size_t)m;
    const float px = points[p3 + 0];
    const float py = points[p3 + 1];
    const float pz = points[p3 + 2];

    const float fx = floorf(px), fy = floorf(py), fz = floorf(pz);
    const int bx = (int)fx, by = (int)fy, bz = (int)fz;

    const float dxc = fx + 0.5f - px;
    const float dyc = fy + 0.5f - py;
    const float dzc = fz + 0.5f - pz;

    const int nx = (dxc > 0.f) ? 1 : ((dxc < 0.f) ? -1 : 0);
    const int ny = (dyc > 0.f) ? 1 : ((dyc < 0.f) ? -1 : 0);
    const int nz = (dzc > 0.f) ? 1 : ((dzc < 0.f) ? -1 : 0);

    const float ax = fabsf(dxc), ay = fabsf(dyc), az = fabsf(dzc);
    const float axi = 1.f - ax, ayi = 1.f - ay, azi = 1.f - az;

    // shared z-pair bookkeeping (same for all 4 xy corners)
    const int cz0 = bz;                       // oz = 0 corner z (unclamped)
    const int cz1 = bz + nz;                  // oz = 1 corner z (unclamped)
    const int zlo = min(max(bz + min(nz, 0), 0), 254);
    const int ccz0 = min(max(cz0, 0), 255);
    const int ccz1 = min(max(cz1, 0), 255);
    const int sel0 = ccz0 - zlo;              // 0 or 1: which half of entry
    const int sel1 = ccz1 - zlo;
    const bool vz0 = ((unsigned)cz0 < 256u);
    const bool vz1 = ((unsigned)cz1 < 256u);

    float fv = 0.f, fw = 0.f;
    float idxf[24];
    float wts[8];

#pragma unroll
    for (int q = 0; q < 4; ++q) {             // q -> (ox, oy); corners c=2q, 2q+1
        const int ox = q >> 1;
        const int oy = q & 1;
        const int cx = bx + (ox ? nx : 0);
        const int cy = by + (oy ? ny : 0);
        const bool vxy = ((unsigned)cx < 256u) & ((unsigned)cy < 256u);
        const int ccx = min(max(cx, 0), 255);
        const int ccy = min(max(cy, 0), 255);
        const float wxy = (ox ? ax : axi) * (oy ? ay : ayi);

        const int entry = (((((ccx >> 1) << 7) | (ccy >> 1)) << 8 | zlo) << 2)
                        | (((ccx & 1) << 1) | (ccy & 1));
        const v4f qv = *reinterpret_cast<const v4f*>(packed + ((size_t)entry << 2));

        // corner oz = 0  (c = 4*ox + 2*oy + 0 = 2q)
        {
            const float t  = sel0 ? qv.z : qv.x;
            const float wv = sel0 ? qv.w : qv.y;
            const float vm = (vxy & vz0) ? 1.f : 0.f;
            const float w  = wxy * azi;
            fv += (t * vm) * w;
            fw += (wv * vm) * w;
            const int c = 2 * q;
            idxf[c * 3 + 0] = (float)cx;
            idxf[c * 3 + 1] = (float)cy;
            idxf[c * 3 + 2] = (float)cz0;
            wts[c] = w;
        }
        // corner oz = 1  (c = 2q + 1)
        {
            const float t  = sel1 ? qv.z : qv.x;
            const float wv = sel1 ? qv.w : qv.y;
            const float vm = (vxy & vz1) ? 1.f : 0.f;
            const float w  = wxy * az;
            fv += (t * vm) * w;
            fw += (wv * vm) * w;
            const int c = 2 * q + 1;
            idxf[c * 3 + 0] = (float)cx;
            idxf[c * 3 + 1] = (float)cy;
            idxf[c * 3 + 2] = (float)cz1;
            wts[c] = w;
        }
    }

    const size_t Ms = (size_t)M;
    out[m] = fv;
    out[33 * Ms + m] = fw;

    float4* __restrict__ oi = reinterpret_cast<float4*>(out + Ms + (size_t)m * 24);
    const float4* ii = reinterpret_cast<const float4*>(idxf);
#pragma unroll
    for (int i = 0; i < 6; ++i) oi[i] = ii[i];

    float4* __restrict__ ow = reinterpret_cast<float4*>(out + 25 * Ms + (size_t)m * 8);
    const float4* wi = reinterpret_cast<const float4*>(wts);
    ow[0] = wi[0];
    ow[1] = wi[1];
}

// ---------------- v4 fallback: 2x2x2 brick layout (134 MB ws) --------------
__global__ __launch_bounds__(256) void pack_brick_kernel(
    const float* __restrict__ tsdf,
    const float* __restrict__ wvol,
    float* __restrict__ packed)
{
    const int t = blockIdx.x * 256 + threadIdx.x;
    const int bz = t & 127;
    const int by = (t >> 7) & 127;
    const int bx = t >> 14;
    const int x0 = bx << 1, y0 = by << 1, z0 = bz << 1;

    v4f o[4];
#pragma unroll
    for (int dx = 0; dx < 2; ++dx) {
#pragma unroll
        for (int dy = 0; dy < 2; ++dy) {
            const size_t src = ((size_t)(x0 + dx) << 16) |
                               (size_t)((y0 + dy) << 8) | (size_t)z0;
            const v2f tp = *reinterpret_cast<const v2f*>(tsdf + src);
            const v2f wp = *reinterpret_cast<const v2f*>(wvol + src);
            v4f o4; o4.x = tp.x; o4.y = wp.x; o4.z = tp.y; o4.w = wp.y;
            o[dx * 2 + dy] = o4;
        }
    }
    v4f* __restrict__ dst = reinterpret_cast<v4f*>(packed + ((size_t)t << 4));
    dst[0] = o[0];
    dst[1] = o[1];
    dst[2] = o[2];
    dst[3] = o[3];
}

__global__ __launch_bounds__(256) void extractor_packed(
    const float* __restrict__ points,
    const float* __restrict__ packed,
    float* __restrict__ out,
    int M)
{
    const int m = blockIdx.x * 256 + threadIdx.x;
    if (m >= M) return;

    const size_t p3 = 3ull * (size_t)m;
    const float px = points[p3 + 0];
    const float py = points[p3 + 1];
    const float pz = points[p3 + 2];

    const float fx = floorf(px), fy = floorf(py), fz = floorf(pz);
    const int bx = (int)fx, by = (int)fy, bz = (int)fz;

    const float dxc = fx + 0.5f - px;
    const float dyc = fy + 0.5f - py;
    const float dzc = fz + 0.5f - pz;

    const int nx = (dxc > 0.f) ? 1 : ((dxc < 0.f) ? -1 : 0);
    const int ny = (dyc > 0.f) ? 1 : ((dyc < 0.f) ? -1 : 0);
    const int nz = (dzc > 0.f) ? 1 : ((dzc < 0.f) ? -1 : 0);

    const float ax = fabsf(dxc), ay = fabsf(dyc), az = fabsf(dzc);
    const float axi = 1.f - ax, ayi = 1.f - ay, azi = 1.f - az;

    float fv = 0.f, fw = 0.f;
    float idxf[24];
    float wts[8];

#pragma unroll
    for (int c = 0; c < 8; ++c) {
        const int ox = (c >> 2) & 1;
        const int oy = (c >> 1) & 1;
        const int oz = c & 1;
        const int cx = bx + (ox ? nx : 0);
        const int cy = by + (oy ? ny : 0);
        const int cz = bz + (oz ? nz : 0);
        const float w = (ox ? ax : axi) * (oy ? ay : ayi) * (oz ? az : azi);
        const bool valid = ((unsigned)cx < 256u) & ((unsigned)cy < 256u) & ((unsigned)cz < 256u);
        const int ccx = min(max(cx, 0), 255);
        const int ccy = min(max(cy, 0), 255);
        const int ccz = min(max(cz, 0), 255);
        const int brick = ((ccx >> 1) << 14) | ((ccy >> 1) << 7) | (ccz >> 1);
        const int off = ((ccx & 1) << 2) | ((ccy & 1) << 1) | (ccz & 1);
        const size_t fidx = ((size_t)brick << 4) + (size_t)(off << 1);
        const float vm = valid ? 1.f : 0.f;
        const v2f tw = *reinterpret_cast<const v2f*>(packed + fidx);
        fv += tw.x * vm * w;
        fw += tw.y * vm * w;
        idxf[c * 3 + 0] = (float)cx;
        idxf[c * 3 + 1] = (float)cy;
        idxf[c * 3 + 2] = (float)cz;
        wts[c] = w;
    }

    const size_t Ms = (size_t)M;
    out[m] = fv;
    out[33 * Ms + m] = fw;

    float4* __restrict__ oi = reinterpret_cast<float4*>(out + Ms + (size_t)m * 24);
    const float4* ii = reinterpret_cast<const float4*>(idxf);
#pragma unroll
    for (int i = 0; i < 6; ++i) oi[i] = ii[i];

    float4* __restrict__ ow = reinterpret_cast<float4*>(out + 25 * Ms + (size_t)m * 8);
    const float4* wi = reinterpret_cast<const float4*>(wts);
    ow[0] = wi[0];
    ow[1] = wi[1];
}

// ---------------- v1 fallback: no workspace ---------------------------------
__global__ __launch_bounds__(256) void extractor_kernel(
    const float* __restrict__ points,
    const float* __restrict__ tsdf,
    const float* __restrict__ wvol,
    float* __restrict__ out,
    int M)
{
    const int m = blockIdx.x * 256 + threadIdx.x;
    if (m >= M) return;

    const size_t p3 = 3ull * (size_t)m;
    const float px = points[p3 + 0];
    const float py = points[p3 + 1];
    const float pz = points[p3 + 2];

    const float fx = floorf(px), fy = floorf(py), fz = floorf(pz);
    const int bx = (int)fx, by = (int)fy, bz = (int)fz;

    const float dxc = fx + 0.5f - px;
    const float dyc = fy + 0.5f - py;
    const float dzc = fz + 0.5f - pz;

    const int nx = (dxc > 0.f) ? 1 : ((dxc < 0.f) ? -1 : 0);
    const int ny = (dyc > 0.f) ? 1 : ((dyc < 0.f) ? -1 : 0);
    const int nz = (dzc > 0.f) ? 1 : ((dzc < 0.f) ? -1 : 0);

    const float ax = fabsf(dxc), ay = fabsf(dyc), az = fabsf(dzc);
    const float axi = 1.f - ax, ayi = 1.f - ay, azi = 1.f - az;

    float fv = 0.f, fw = 0.f;
    float idxf[24];
    float wts[8];

#pragma unroll
    for (int c = 0; c < 8; ++c) {
        const int ox = (c >> 2) & 1;
        const int oy = (c >> 1) & 1;
        const int oz = c & 1;
        const int cx = bx + (ox ? nx : 0);
        const int cy = by + (oy ? ny : 0);
        const int cz = bz + (oz ? nz : 0);
        const float w = (ox ? ax : axi) * (oy ? ay : ayi) * (oz ? az : azi);
        const bool valid = ((unsigned)cx < 256u) & ((unsigned)cy < 256u) & ((unsigned)cz < 256u);
        const int ccx = min(max(cx, 0), 255);
        const int ccy = min(max(cy, 0), 255);
        const int ccz = min(max(cz, 0), 255);
        const int flat = (ccx << 16) | (ccy << 8) | ccz;
        const float vm = valid ? 1.f : 0.f;
        const float tv = tsdf[flat] * vm;
        const float wv = wvol[flat] * vm;
        fv += tv * w;
        fw += wv * w;
        idxf[c * 3 + 0] = (float)cx;
        idxf[c * 3 + 1] = (float)cy;
        idxf[c * 3 + 2] = (float)cz;
        wts[c] = w;
    }

    const size_t Ms = (size_t)M;
    out[m] = fv;
    out[33 * Ms + m] = fw;

    float4* __restrict__ oi = reinterpret_cast<float4*>(out + Ms + (size_t)m * 24);
    const float4* ii = reinterpret_cast<const float4*>(idxf);
#pragma unroll
    for (int i = 0; i < 6; ++i) oi[i] = ii[i];

    float4* __restrict__ ow = reinterpret_cast<float4*>(out + 25 * Ms + (size_t)m * 8);
    const float4* wi = reinterpret_cast<const float4*>(wts);
    ow[0] = wi[0];
    ow[1] = wi[1];
}

extern "C" void kernel_launch(void* const* d_in, const int* in_sizes, int n_in,
                              void* d_out, int out_size, void* d_ws, size_t ws_size,
                              hipStream_t stream) {
    const float* points = (const float*)d_in[0];
    const float* tsdf   = (const float*)d_in[1];
    const float* wvol   = (const float*)d_in[2];
    float* out = (float*)d_out;

    const int M = in_sizes[0] / 3;               // B*H*N
    const int blocks = (M + 255) / 256;

    const size_t need_zdup  = 268435456ull;      // 256 MiB: 16384*256*4 * 16 B
    const size_t need_brick = 134217728ull;      // 128 MiB: 128^3 * 64 B

    if (ws_size >= need_zdup) {
        float* packed = (float*)d_ws;
        const int nthreads = 16384 * 256;        // one per 64 B sector
        pack_zdup_kernel<<<nthreads / 256, 256, 0, stream>>>(tsdf, wvol, packed);
        extractor_zdup<<<blocks, 256, 0, stream>>>(points, packed, out, M);
    } else if (ws_size >= need_brick) {
        float* packed = (float*)d_ws;
        const int nbricks = 128 * 128 * 128;
        pack_brick_kernel<<<nbricks / 256, 256, 0, stream>>>(tsdf, wvol, packed);
        extractor_packed<<<blocks, 256, 0, stream>>>(points, packed, out, M);
    } else {
        extractor_kernel<<<blocks, 256, 0, stream>>>(points, tsdf, wvol, out, M);
    }
}